// Round 7
// baseline (617.086 us; speedup 1.0000x reference)
//
#include <hip/hip_runtime.h>
#include <hip/hip_cooperative_groups.h>

namespace cg = cooperative_groups;

// ViT cls-token-only forward, single cooperative kernel. B=16, C=8, D=511,
// DIM=2048, SEQ=512, NH=16, HD=128.
// q = (cls+pos0) @ Wq + bq (batch-independent); r[h] = SCALE * Wk_h @ q_h;
// scores[b,h,j] = tok[b,j].r[h]; softmax; u[b,h] = sum_j p tok[b,j];
// ao = u @ Wv + bv; out = ao @ proj_w + proj_b.
//
// R7: all 7 kernels + 2 memsets fused into ONE cooperative launch with 7
// grid.sync()s — R6's profile showed every kernel <40 µs but ~60-75 µs of
// per-dispatch overhead across 9 stream-ordered dispatches. Phase bodies are
// byte-identical math to R6. 512 blocks x 256 thr = 2 blocks/CU co-resident
// (LDS 33.3 KB/block, launch_bounds (256,2)).

#define BB   16
#define CC   8
#define DD   511
#define DIM  2048
#define SEQ  512
#define NH   16
#define HD   128
#define W3   6144
#define SCALE 0.08838834764831845f
#define GRID 512

// workspace layout (float offsets); [0, ZERO_N) zeroed in phase 0
#define Q_OFF   0            // 2048    atomic
#define G_OFF   2048         // 16      atomic
#define AO_OFF  2064         // 32768   atomic
#define SC_OFF  34832        // 131072  atomic (scores), softmax in place
#define ZERO_N  165904
#define R_OFF   165904       // 32768   fp32 r (plain write)
#define RB_OFF  198672       // 32768 float slots = 65536 shorts: r bf16 hi/lo
#define U_OFF   231440       // 524288  u (plain write)

#define PSTR 520

typedef __attribute__((ext_vector_type(8))) short short8;
typedef __attribute__((ext_vector_type(4))) float floatx4;

static __device__ inline short bf_hi(float f) {
  return (short)(__float_as_uint(f) >> 16);          // truncate to bf16
}
static __device__ inline float bf_hif(float f) {
  return __uint_as_float(__float_as_uint(f) & 0xffff0000u);
}

struct PVShared { short phl[NH * PSTR]; short pll[NH * PSTR]; };  // 33,280 B
union Shared {
  PVShared pv;
  float qs[HD];
  float red[256];
  float us[2][32][20];
  float as[32][20];
};

__global__ __launch_bounds__(256, 2) void vit_fused(
    const float* __restrict__ x, const float* __restrict__ pos,
    const float* __restrict__ cls, const float* __restrict__ qkv_w,
    const float* __restrict__ qkv_b, const float* __restrict__ proj_w,
    const float* __restrict__ proj_b, float* __restrict__ ws,
    float* __restrict__ out) {
  cg::grid_group grid = cg::this_grid();
  __shared__ Shared sh;
  const int blk = blockIdx.x;   // 0..511
  const int t   = threadIdx.x;  // 0..255

  // ---- P0: zero atomic accumulators (q, gamma, ao, scores) + out ----
  for (int i = blk * 256 + t; i < ZERO_N; i += GRID * 256) ws[i] = 0.f;
  for (int i = blk * 256 + t; i < BB * DIM; i += GRID * 256) out[i] = 0.f;
  grid.sync();

  // ---- P1: q[n] = sum_d (cls+pos)[d] * Wq[d][n] + bq[n] ----
  // blk -> (nt 0..7, dch 0..63 of 32 d)
  {
    int nt = blk & 7, dch = blk >> 3;
    int n = nt * 256 + t, d0 = dch * 32;
    float acc = (dch == 0) ? qkv_b[n] : 0.f;
#pragma unroll 8
    for (int d = d0; d < d0 + 32; ++d) {
      float t0 = cls[d] + pos[d];         // uniform -> scalar load
      acc += t0 * qkv_w[(size_t)d * W3 + n];
    }
    atomicAdd(&ws[Q_OFF + n], acc);
  }
  grid.sync();

  // ---- P2: r[h][d] (+ bf16 hi/lo) and gamma[h] (blocks 0..127) ----
  if (blk < 128) {
    int h = blk >> 3, dt = blk & 7;
    int d = dt * 256 + t;
    if (t < HD) sh.qs[t] = ws[Q_OFF + h * HD + t];
    __syncthreads();
    const float4* w4 = reinterpret_cast<const float4*>(
        qkv_w + (size_t)d * W3 + DIM + h * HD);
    float acc = 0.f;
#pragma unroll 8
    for (int e4 = 0; e4 < 32; ++e4) {
      float4 w = w4[e4];
      acc += sh.qs[e4*4+0]*w.x + sh.qs[e4*4+1]*w.y
           + sh.qs[e4*4+2]*w.z + sh.qs[e4*4+3]*w.w;
    }
    float r = acc * SCALE;
    int i = h * DIM + d;
    ws[R_OFF + i] = r;
    short* rb = (short*)(ws + RB_OFF);
    rb[i] = bf_hi(r);
    rb[NH * DIM + i] = bf_hi(r - bf_hif(r));
    float g = (cls[d] + pos[d]) * r;      // fused gamma partial
    for (int m = 1; m < 64; m <<= 1) g += __shfl_xor(g, m, 64);
    if ((t & 63) == 0) atomicAdd(&ws[G_OFF + h], g);
  }
  grid.sync();

  // ---- P3: scores via MFMA. blk -> (jt2 0..7, b 0..15, ks 0..3);
  //      wave w handles j-tile jt = jt2*4+w; 3-term hi/lo compensation ----
  {
    int jt2 = blk & 7, b = (blk >> 3) & 15, ks = blk >> 7;
    int w = t >> 6, l = t & 63;
    int jt = jt2 * 4 + w;
    int m16 = l & 15, kg = l >> 4;
    int jrow = 1 + jt * 16 + m16;
    int jc = jrow < SEQ ? jrow : (SEQ - 1);
    const size_t xrow = (size_t)b * CC * DD * 256 + (size_t)(jc - 1) * 256;
    const short* rh = (const short*)(ws + RB_OFF);
    const short* rl = rh + NH * DIM;
    floatx4 acc = {0.f, 0.f, 0.f, 0.f};
#pragma unroll 2
    for (int kk = ks * 16; kk < ks * 16 + 16; ++kk) {
      int d0 = kk * 32 + kg * 8;
      int c = d0 >> 8, doff = d0 & 255;
      const float4* xp = reinterpret_cast<const float4*>(
          x + xrow + (size_t)c * DD * 256 + doff);
      const float4* pp = reinterpret_cast<const float4*>(
          pos + (size_t)jc * DIM + d0);
      float4 xa = xp[0], xb = xp[1];
      float4 pa = pp[0], pb = pp[1];
      float f[8] = {xa.x + pa.x, xa.y + pa.y, xa.z + pa.z, xa.w + pa.w,
                    xb.x + pb.x, xb.y + pb.y, xb.z + pb.z, xb.w + pb.w};
      short8 ahi, alo;
#pragma unroll
      for (int i = 0; i < 8; ++i) {
        ahi[i] = bf_hi(f[i]);
        alo[i] = bf_hi(f[i] - bf_hif(f[i]));
      }
      short8 bhi = *reinterpret_cast<const short8*>(rh + m16 * DIM + d0);
      short8 blo = *reinterpret_cast<const short8*>(rl + m16 * DIM + d0);
      acc = __builtin_amdgcn_mfma_f32_16x16x32_bf16(ahi, bhi, acc, 0, 0, 0);
      acc = __builtin_amdgcn_mfma_f32_16x16x32_bf16(ahi, blo, acc, 0, 0, 0);
      acc = __builtin_amdgcn_mfma_f32_16x16x32_bf16(alo, bhi, acc, 0, 0, 0);
    }
    // C layout: col(h) = l&15, row(j) = (l>>4)*4 + reg  [m89-verified]
    int h = m16;
#pragma unroll
    for (int reg = 0; reg < 4; ++reg) {
      int row = kg * 4 + reg;
      int j = 1 + jt * 16 + row;
      if (j < SEQ)
        atomicAdd(&ws[SC_OFF + (size_t)(b * NH + h) * SEQ + j], acc[reg]);
    }
  }
  grid.sync();

  // ---- P4: softmax per (b,h), in place; j=0 score = gamma[h] (blk<256) ----
  if (blk < 256) {
    int h = blk & 15, b = blk >> 4;
    float* sc = ws + SC_OFF + (size_t)(b * NH + h) * SEQ;
    float s0 = (t == 0) ? ws[G_OFF + h] : sc[t];
    float s1 = sc[t + 256];
    sh.red[t] = fmaxf(s0, s1);
    __syncthreads();
    for (int s = 128; s > 0; s >>= 1) {
      if (t < s) sh.red[t] = fmaxf(sh.red[t], sh.red[t + s]);
      __syncthreads();
    }
    float m = sh.red[0];
    __syncthreads();
    float e0 = __expf(s0 - m), e1 = __expf(s1 - m);
    sh.red[t] = e0 + e1;
    __syncthreads();
    for (int s = 128; s > 0; s >>= 1) {
      if (t < s) sh.red[t] += sh.red[t + s];
      __syncthreads();
    }
    float inv = 1.f / sh.red[0];
    sc[t] = e0 * inv;
    sc[t + 256] = e1 * inv;
  }
  grid.sync();

  // ---- P5: u[b] = p[b] @ tok[b] via MFMA. blk -> (dt 0..31, b 0..15);
  //      p staged in LDS bf16 hi/lo; cls folded in at j=0 ----
  {
    int dt = blk & 31, b = blk >> 5;
    const float* pb = ws + SC_OFF + (size_t)b * NH * SEQ;
    for (int i = t; i < NH * SEQ; i += 256) {
      int h = i >> 9, j = i & 511;
      float v = pb[h * SEQ + j];
      sh.pv.phl[h * PSTR + j] = bf_hi(v);
      sh.pv.pll[h * PSTR + j] = bf_hi(v - bf_hif(v));
    }
    __syncthreads();
    int w = t >> 6, l = t & 63;
    int m16 = l & 15, kq = l >> 4;
    int dcol = dt * 64 + w * 16 + m16;
    int c = dcol >> 8, doff = dcol & 255;
    const float* xcol = x + (size_t)b * CC * DD * 256 + (size_t)c * DD * 256 + doff;
    const float* pcol = pos + dcol;
    float clsv0 = cls[dcol];
    const short8* pph = reinterpret_cast<const short8*>(&sh.pv.phl[m16 * PSTR]);
    const short8* ppl = reinterpret_cast<const short8*>(&sh.pv.pll[m16 * PSTR]);
    floatx4 acc = {0.f, 0.f, 0.f, 0.f};
    for (int kk = 0; kk < 16; ++kk) {
      int jb = kk * 32 + kq * 8;
      const float* xp = xcol + ((size_t)jb - 1) * 256;
      const float* xp_safe = (jb == 0) ? xcol : xp;   // keep load in-bounds
      float f[8];
      float x0 = xp_safe[0];
      f[0] = ((jb == 0) ? clsv0 : x0) + pcol[(size_t)jb * DIM];
#pragma unroll
      for (int e = 1; e < 8; ++e)
        f[e] = xp[(size_t)e * 256] + pcol[(size_t)(jb + e) * DIM];
      short8 thi, tlo;
#pragma unroll
      for (int i = 0; i < 8; ++i) {
        thi[i] = bf_hi(f[i]);
        tlo[i] = bf_hi(f[i] - bf_hif(f[i]));
      }
      short8 phi = pph[kk * 4 + kq];
      short8 plo = ppl[kk * 4 + kq];
      acc = __builtin_amdgcn_mfma_f32_16x16x32_bf16(phi, thi, acc, 0, 0, 0);
      acc = __builtin_amdgcn_mfma_f32_16x16x32_bf16(phi, tlo, acc, 0, 0, 0);
      acc = __builtin_amdgcn_mfma_f32_16x16x32_bf16(plo, thi, acc, 0, 0, 0);
    }
    float* ub = ws + U_OFF + (size_t)b * NH * DIM + dcol;
#pragma unroll
    for (int reg = 0; reg < 4; ++reg) {
      int h = kq * 4 + reg;
      ub[(size_t)h * DIM] = acc[reg];
    }
  }
  grid.sync();

  // ---- P6: ao[b][m] += u @ Wv chunk (+bv). blk -> (nt 0..7, dc 0..63);
  //      all 16 batches per block -> Wv read once ----
  {
    int nt = blk & 7, dc = blk >> 3;
    int m = nt * 256 + t;
    int h0 = nt * 2;
    int d0 = dc * 32;
    for (int i = t; i < 2 * 32 * BB; i += 256) {
      int dd = i & 31, b = (i >> 5) & 15, hh = i >> 9;
      sh.us[hh][dd][b] = ws[U_OFF + (size_t)(b * NH + h0 + hh) * DIM + d0 + dd];
    }
    __syncthreads();
    int hl = t >> 7;
    float acc[BB];
#pragma unroll
    for (int b = 0; b < BB; ++b) acc[b] = 0.f;
    const float* wcol = qkv_w + (size_t)d0 * W3 + 2 * DIM + m;
#pragma unroll 4
    for (int dd = 0; dd < 32; ++dd) {
      float w = wcol[(size_t)dd * W3];
      const float4* u4 = reinterpret_cast<const float4*>(&sh.us[hl][dd][0]);
      float4 u0 = u4[0], u1 = u4[1], u2 = u4[2], u3 = u4[3];  // broadcast
      acc[0]  += u0.x * w; acc[1]  += u0.y * w; acc[2]  += u0.z * w; acc[3]  += u0.w * w;
      acc[4]  += u1.x * w; acc[5]  += u1.y * w; acc[6]  += u1.z * w; acc[7]  += u1.w * w;
      acc[8]  += u2.x * w; acc[9]  += u2.y * w; acc[10] += u2.z * w; acc[11] += u2.w * w;
      acc[12] += u3.x * w; acc[13] += u3.y * w; acc[14] += u3.z * w; acc[15] += u3.w * w;
    }
    float bias = (dc == 0) ? qkv_b[2 * DIM + m] : 0.f;
#pragma unroll
    for (int b = 0; b < BB; ++b)
      atomicAdd(&ws[AO_OFF + b * DIM + m], acc[b] + bias);
  }
  grid.sync();

  // ---- P7: out[b][n] += ao @ proj_w chunk (+pb). blk -> (nt, mc) ----
  {
    int nt = blk & 7, mc = blk >> 3;
    int n = nt * 256 + t;
    int m0 = mc * 32;
    for (int i = t; i < 32 * BB; i += 256) {
      int mm = i & 31, b = i >> 5;
      sh.as[mm][b] = ws[AO_OFF + b * DIM + m0 + mm];
    }
    __syncthreads();
    float acc[BB];
#pragma unroll
    for (int b = 0; b < BB; ++b) acc[b] = 0.f;
    const float* wcol = proj_w + (size_t)m0 * DIM + n;
#pragma unroll 4
    for (int mm = 0; mm < 32; ++mm) {
      float w = wcol[(size_t)mm * DIM];
      const float4* a4 = reinterpret_cast<const float4*>(&sh.as[mm][0]);
      float4 a0 = a4[0], a1 = a4[1], a2 = a4[2], a3 = a4[3];  // broadcast
      acc[0]  += a0.x * w; acc[1]  += a0.y * w; acc[2]  += a0.z * w; acc[3]  += a0.w * w;
      acc[4]  += a1.x * w; acc[5]  += a1.y * w; acc[6]  += a1.z * w; acc[7]  += a1.w * w;
      acc[8]  += a2.x * w; acc[9]  += a2.y * w; acc[10] += a2.z * w; acc[11] += a2.w * w;
      acc[12] += a3.x * w; acc[13] += a3.y * w; acc[14] += a3.z * w; acc[15] += a3.w * w;
    }
    float bias = (mc == 0) ? proj_b[n] : 0.f;
#pragma unroll
    for (int b = 0; b < BB; ++b)
      atomicAdd(&out[b * DIM + n], acc[b] + bias);
  }
}

extern "C" void kernel_launch(void* const* d_in, const int* in_sizes, int n_in,
                              void* d_out, int out_size, void* d_ws, size_t ws_size,
                              hipStream_t stream) {
  const float* x      = (const float*)d_in[0];
  const float* pos    = (const float*)d_in[1];
  const float* cls    = (const float*)d_in[2];
  const float* qkv_w  = (const float*)d_in[3];
  const float* qkv_b  = (const float*)d_in[4];
  const float* proj_w = (const float*)d_in[5];
  const float* proj_b = (const float*)d_in[6];
  float* ws  = (float*)d_ws;
  float* out = (float*)d_out;

  void* kargs[] = {(void*)&x, (void*)&pos, (void*)&cls, (void*)&qkv_w,
                   (void*)&qkv_b, (void*)&proj_w, (void*)&proj_b,
                   (void*)&ws, (void*)&out};
  hipLaunchCooperativeKernel((void*)vit_fused, dim3(GRID), dim3(256),
                             kargs, 0, stream);
}

// Round 8
// 220.088 us; speedup vs baseline: 2.8038x; 2.8038x over previous
//
#include <hip/hip_runtime.h>

// ViT cls-token-only forward. B=16, C=8, D=511, DIM=2048, SEQ=512, NH=16.
// q = (cls+pos0) @ Wq + bq (batch-independent); r[h] = SCALE * Wk_h @ q_h;
// scores[b,h,j] = tok[b,j].r[h]; softmax; u[b,h] = sum_j p tok[b,j];
// ao = u @ Wv + bv; out = ao @ proj_w + proj_b.
//
// R8: revert R7's cooperative fusion (grid.sync ~60 µs each on MI355X across
// 8 XCDs — 7 syncs ate 420 µs). Multi-kernel R6 structure plus:
//  - k0_prep: zeroes ws atomics + out AND transposes pos -> posT (4 MB);
//    replaces 2 hipMemsetAsync dispatches.
//  - k4 softmax fused into k5's p-staging (raw scores + gamma -> LDS bf16
//    hi/lo per block; p never round-trips global). Dispatches 9 -> 7.
//  - k5 reads pos via posT: contiguous 32 B per k-step instead of 8 KB-stride
//    scatter.
//  - k3 re-blocked 2048x64 -> 512x256 (same waves, 1/4 the blocks).

#define BB   16
#define CC   8
#define DD   511
#define DIM  2048
#define SEQ  512
#define NH   16
#define HD   128
#define W3   6144
#define SCALE 0.08838834764831845f

// workspace layout (float offsets); [0, ZERO_N) zeroed by k0_prep
#define Q_OFF   0            // 2048    atomic
#define G_OFF   2048         // 16      atomic
#define AO_OFF  2064         // 32768   atomic
#define SC_OFF  34832        // 131072  atomic raw scores (j=0 stays 0)
#define ZERO_N  165904
#define R_OFF   165904       // 32768   fp32 r (plain write)
#define RB_OFF  198672       // 32768 float slots = 65536 shorts: r bf16 hi/lo
#define U_OFF   231440       // 524288  u (plain write)
#define POST_OFF 755728      // 1048576 posT[d][j] (plain write)
// total = 1,804,304 floats ~= 7.2 MB

#define PSTR 520

typedef __attribute__((ext_vector_type(8))) short short8;
typedef __attribute__((ext_vector_type(4))) float floatx4;

static __device__ inline short bf_hi(float f) {
  return (short)(__float_as_uint(f) >> 16);          // truncate to bf16
}
static __device__ inline float bf_hif(float f) {
  return __uint_as_float(__float_as_uint(f) & 0xffff0000u);
}

// K0: zero atomic accumulators + out; transpose pos -> posT. grid (16 jt, 64 dt).
__global__ __launch_bounds__(256) void k0_prep(
    const float* __restrict__ pos, float* __restrict__ ws,
    float* __restrict__ out) {
  int blk = blockIdx.x + blockIdx.y * 16;
  int t = threadIdx.x;
  for (int i = blk * 256 + t; i < ZERO_N; i += 1024 * 256) ws[i] = 0.f;
  for (int i = blk * 256 + t; i < BB * DIM; i += 1024 * 256) out[i] = 0.f;
  __shared__ float tile[32][33];
  int jt = blockIdx.x, dt = blockIdx.y;
  int tx = t & 31, ty = t >> 5;          // 32 x 8
#pragma unroll
  for (int r = 0; r < 32; r += 8)
    tile[ty + r][tx] = pos[(size_t)(jt * 32 + ty + r) * DIM + dt * 32 + tx];
  __syncthreads();
  float* pt = ws + POST_OFF;
#pragma unroll
  for (int r = 0; r < 32; r += 8)
    pt[(size_t)(dt * 32 + ty + r) * SEQ + jt * 32 + tx] = tile[tx][ty + r];
}

// K1: q[n] = sum_d (cls[d]+pos[d]) * Wq[d][n] + bq[n]   grid (8 ntile, 64 dchunk)
__global__ __launch_bounds__(256) void k1_q(
    const float* __restrict__ pos, const float* __restrict__ cls,
    const float* __restrict__ qkv_w, const float* __restrict__ qkv_b,
    float* __restrict__ ws) {
  int n  = blockIdx.x * 256 + threadIdx.x;
  int d0 = blockIdx.y * 32;
  float acc = (blockIdx.y == 0) ? qkv_b[n] : 0.f;
#pragma unroll 8
  for (int d = d0; d < d0 + 32; ++d) {
    float t0 = cls[d] + pos[d];           // uniform -> scalar load
    acc += t0 * qkv_w[(size_t)d * W3 + n];
  }
  atomicAdd(&ws[Q_OFF + n], acc);
}

// K2: r[h][d] = SCALE * (Wk[d, h-slice] . q[h-slice]); writes fp32 r, bf16
// hi/lo, AND accumulates gamma[h] = tok0 . r[h]. grid (16 dtile, 16 h), 128 thr.
__global__ __launch_bounds__(128) void k2_r(
    const float* __restrict__ qkv_w, const float* __restrict__ pos,
    const float* __restrict__ cls, float* __restrict__ ws) {
  __shared__ float qs[HD];
  int h = blockIdx.y;
  int d = blockIdx.x * 128 + threadIdx.x;
  if (threadIdx.x < HD) qs[threadIdx.x] = ws[Q_OFF + h * HD + threadIdx.x];
  __syncthreads();
  const float4* w4 = reinterpret_cast<const float4*>(
      qkv_w + (size_t)d * W3 + DIM + h * HD);
  float acc = 0.f;
#pragma unroll 8
  for (int e4 = 0; e4 < 32; ++e4) {
    float4 w = w4[e4];
    acc += qs[e4*4+0]*w.x + qs[e4*4+1]*w.y + qs[e4*4+2]*w.z + qs[e4*4+3]*w.w;
  }
  float r = acc * SCALE;
  int i = h * DIM + d;
  ws[R_OFF + i] = r;
  short* rb = (short*)(ws + RB_OFF);
  rb[i] = bf_hi(r);
  rb[NH * DIM + i] = bf_hi(r - bf_hif(r));
  float g = (cls[d] + pos[d]) * r;        // fused gamma partial
  for (int m = 1; m < 64; m <<= 1) g += __shfl_xor(g, m, 64);
  if ((threadIdx.x & 63) == 0) atomicAdd(&ws[G_OFF + h], g);
}

// K3: scores[b,h,j] for j>=1 via MFMA, 3-term hi/lo. grid (8 jt2, 16 b, 4 ks),
// 256 thr = 4 waves; wave w owns j-tile jt = jt2*4+w.
__global__ __launch_bounds__(256) void k3_scores_mfma(
    const float* __restrict__ x, const float* __restrict__ pos,
    float* __restrict__ ws) {
  int jt2 = blockIdx.x, b = blockIdx.y, ks = blockIdx.z;
  int t = threadIdx.x;
  int w = t >> 6, l = t & 63;
  int jt = jt2 * 4 + w;
  int m16 = l & 15, kg = l >> 4;
  int jrow = 1 + jt * 16 + m16;
  int jc = jrow < SEQ ? jrow : (SEQ - 1);   // clamp; jrow==512 masked at store
  const size_t xrow = (size_t)b * CC * DD * 256 + (size_t)(jc - 1) * 256;
  const short* rh = (const short*)(ws + RB_OFF);
  const short* rl = rh + NH * DIM;
  floatx4 acc = {0.f, 0.f, 0.f, 0.f};
#pragma unroll 2
  for (int kk = ks * 16; kk < ks * 16 + 16; ++kk) {
    int d0 = kk * 32 + kg * 8;
    int c = d0 >> 8, doff = d0 & 255;
    const float4* xp = reinterpret_cast<const float4*>(
        x + xrow + (size_t)c * DD * 256 + doff);
    const float4* pp = reinterpret_cast<const float4*>(
        pos + (size_t)jc * DIM + d0);
    float4 xa = xp[0], xb = xp[1];
    float4 pa = pp[0], pb = pp[1];
    float f[8] = {xa.x + pa.x, xa.y + pa.y, xa.z + pa.z, xa.w + pa.w,
                  xb.x + pb.x, xb.y + pb.y, xb.z + pb.z, xb.w + pb.w};
    short8 ahi, alo;
#pragma unroll
    for (int i = 0; i < 8; ++i) {
      ahi[i] = bf_hi(f[i]);
      alo[i] = bf_hi(f[i] - bf_hif(f[i]));   // f-hi exact, then truncate
    }
    short8 bhi = *reinterpret_cast<const short8*>(rh + m16 * DIM + d0);
    short8 blo = *reinterpret_cast<const short8*>(rl + m16 * DIM + d0);
    acc = __builtin_amdgcn_mfma_f32_16x16x32_bf16(ahi, bhi, acc, 0, 0, 0);
    acc = __builtin_amdgcn_mfma_f32_16x16x32_bf16(ahi, blo, acc, 0, 0, 0);
    acc = __builtin_amdgcn_mfma_f32_16x16x32_bf16(alo, bhi, acc, 0, 0, 0);
  }
  // C layout: col(h) = l&15, row(j) = (l>>4)*4 + reg  [m89-verified]
  int h = m16;
#pragma unroll
  for (int reg = 0; reg < 4; ++reg) {
    int row = kg * 4 + reg;
    int j = 1 + jt * 16 + row;
    if (j < SEQ)
      atomicAdd(&ws[SC_OFF + (size_t)(b * NH + h) * SEQ + j], acc[reg]);
  }
}

// K5: u[b] (16h x 2048d) = softmax(scores[b]) @ tok[b] via MFMA, 3-term
// hi/lo. Softmax fused into the p-staging (raw scores + gamma -> LDS;
// p never touches global). pos via posT (contiguous). grid (32 dt, 16 b).
__global__ __launch_bounds__(256) void k5_pv_mfma(
    const float* __restrict__ x, const float* __restrict__ cls,
    float* __restrict__ ws) {
  int dt = blockIdx.x, b = blockIdx.y, t = threadIdx.x;
  __shared__ short phl[NH * PSTR];
  __shared__ short pll[NH * PSTR];
  int w = t >> 6, l = t & 63;
  // ---- fused softmax: wave w handles rows h = w*4 .. w*4+3 ----
  for (int rr = 0; rr < 4; ++rr) {
    int h = w * 4 + rr;
    const float* sch = ws + SC_OFF + (size_t)(b * NH + h) * SEQ;
    float gam = ws[G_OFF + h];
    float s[8];
#pragma unroll
    for (int i = 0; i < 8; ++i) s[i] = sch[i * 64 + l];
    if (l == 0) s[0] = gam;               // j=0 slot holds the cls score
    float mx = s[0];
#pragma unroll
    for (int i = 1; i < 8; ++i) mx = fmaxf(mx, s[i]);
    for (int m = 1; m < 64; m <<= 1) mx = fmaxf(mx, __shfl_xor(mx, m, 64));
    float e[8], sum = 0.f;
#pragma unroll
    for (int i = 0; i < 8; ++i) { e[i] = __expf(s[i] - mx); sum += e[i]; }
    for (int m = 1; m < 64; m <<= 1) sum += __shfl_xor(sum, m, 64);
    float inv = 1.f / sum;
#pragma unroll
    for (int i = 0; i < 8; ++i) {
      float p = e[i] * inv;
      int j = i * 64 + l;
      phl[h * PSTR + j] = bf_hi(p);
      pll[h * PSTR + j] = bf_hi(p - bf_hif(p));
    }
  }
  __syncthreads();
  // ---- MFMA main loop ----
  int m16 = l & 15, kq = l >> 4;
  int dcol = dt * 64 + w * 16 + m16;
  int c = dcol >> 8, doff = dcol & 255;
  const float* xcol = x + (size_t)b * CC * DD * 256 + (size_t)c * DD * 256 + doff;
  const float* ptcol = ws + POST_OFF + (size_t)dcol * SEQ;
  float clsv0 = cls[dcol];
  const short8* pph = reinterpret_cast<const short8*>(&phl[m16 * PSTR]);
  const short8* ppl = reinterpret_cast<const short8*>(&pll[m16 * PSTR]);
  floatx4 acc = {0.f, 0.f, 0.f, 0.f};
  for (int kk = 0; kk < 16; ++kk) {
    int jb = kk * 32 + kq * 8;
    const float* xp = xcol + ((size_t)jb - 1) * 256;
    const float* xp_safe = (jb == 0) ? xcol : xp;   // keep load in-bounds
    const float4* pt4 = reinterpret_cast<const float4*>(ptcol + jb);
    float4 pt0 = pt4[0], pt1 = pt4[1];
    float ptv[8] = {pt0.x, pt0.y, pt0.z, pt0.w, pt1.x, pt1.y, pt1.z, pt1.w};
    float f[8];
    float x0 = xp_safe[0];
    f[0] = ((jb == 0) ? clsv0 : x0) + ptv[0];
#pragma unroll
    for (int e = 1; e < 8; ++e)
      f[e] = xp[(size_t)e * 256] + ptv[e];
    short8 thi, tlo;
#pragma unroll
    for (int i = 0; i < 8; ++i) {
      thi[i] = bf_hi(f[i]);
      tlo[i] = bf_hi(f[i] - bf_hif(f[i]));
    }
    short8 phi = pph[kk * 4 + kq];
    short8 plo = ppl[kk * 4 + kq];
    acc = __builtin_amdgcn_mfma_f32_16x16x32_bf16(phi, thi, acc, 0, 0, 0);
    acc = __builtin_amdgcn_mfma_f32_16x16x32_bf16(phi, tlo, acc, 0, 0, 0);
    acc = __builtin_amdgcn_mfma_f32_16x16x32_bf16(plo, thi, acc, 0, 0, 0);
  }
  // C: col(d) = l&15, row(h) = kq*4+reg
  float* ub = ws + U_OFF + (size_t)b * NH * DIM + dcol;
#pragma unroll
  for (int reg = 0; reg < 4; ++reg) {
    int h = kq * 4 + reg;
    ub[(size_t)h * DIM] = acc[reg];
  }
}

// K6: ao[b][m] += sum over 32-d chunk of u[b][h][d]*Wv[d][4096+m] (+bv),
// m = h*128+e. ALL 16 batches per block -> Wv read once. grid (8 nt, 64 dc).
__global__ __launch_bounds__(256) void k6_ao(
    const float* __restrict__ qkv_w, const float* __restrict__ qkv_b,
    float* __restrict__ ws) {
  int nt = blockIdx.x, dc = blockIdx.y, t = threadIdx.x;
  int m = nt * 256 + t;
  int h0 = nt * 2;                        // 2 heads per 256-wide n tile
  int d0 = dc * 32;
  __shared__ float us[2][32][20];         // stride 20: 16B-aligned rows
  for (int i = t; i < 2 * 32 * BB; i += 256) {
    int dd = i & 31, b = (i >> 5) & 15, hh = i >> 9;
    us[hh][dd][b] = ws[U_OFF + (size_t)(b * NH + h0 + hh) * DIM + d0 + dd];
  }
  __syncthreads();
  int hl = t >> 7;
  float acc[BB];
#pragma unroll
  for (int b = 0; b < BB; ++b) acc[b] = 0.f;
  const float* wcol = qkv_w + (size_t)d0 * W3 + 2 * DIM + m;
#pragma unroll 4
  for (int dd = 0; dd < 32; ++dd) {
    float w = wcol[(size_t)dd * W3];
    const float4* u4 = reinterpret_cast<const float4*>(&us[hl][dd][0]);
    float4 u0 = u4[0], u1 = u4[1], u2 = u4[2], u3 = u4[3];  // broadcast
    acc[0]  += u0.x * w; acc[1]  += u0.y * w; acc[2]  += u0.z * w; acc[3]  += u0.w * w;
    acc[4]  += u1.x * w; acc[5]  += u1.y * w; acc[6]  += u1.z * w; acc[7]  += u1.w * w;
    acc[8]  += u2.x * w; acc[9]  += u2.y * w; acc[10] += u2.z * w; acc[11] += u2.w * w;
    acc[12] += u3.x * w; acc[13] += u3.y * w; acc[14] += u3.z * w; acc[15] += u3.w * w;
  }
  float bias = (dc == 0) ? qkv_b[2 * DIM + m] : 0.f;
#pragma unroll
  for (int b = 0; b < BB; ++b)
    atomicAdd(&ws[AO_OFF + b * DIM + m], acc[b] + bias);
}

// K7: out[b][n] += sum over 32-m chunk of ao[b][m]*proj_w[m][n] (+pb).
// ALL 16 batches per block -> proj_w read once. grid (8 nt, 64 mc).
__global__ __launch_bounds__(256) void k7_out(
    const float* __restrict__ proj_w, const float* __restrict__ proj_b,
    const float* __restrict__ ws, float* __restrict__ out) {
  int nt = blockIdx.x, mc = blockIdx.y, t = threadIdx.x;
  int n = nt * 256 + t;
  int m0 = mc * 32;
  __shared__ float as[32][20];
  for (int i = t; i < 32 * BB; i += 256) {
    int mm = i & 31, b = i >> 5;
    as[mm][b] = ws[AO_OFF + b * DIM + m0 + mm];
  }
  __syncthreads();
  float acc[BB];
#pragma unroll
  for (int b = 0; b < BB; ++b) acc[b] = 0.f;
  const float* wcol = proj_w + (size_t)m0 * DIM + n;
#pragma unroll 4
  for (int mm = 0; mm < 32; ++mm) {
    float w = wcol[(size_t)mm * DIM];
    const float4* a4 = reinterpret_cast<const float4*>(&as[mm][0]);
    float4 a0 = a4[0], a1 = a4[1], a2 = a4[2], a3 = a4[3];  // broadcast
    acc[0]  += a0.x * w; acc[1]  += a0.y * w; acc[2]  += a0.z * w; acc[3]  += a0.w * w;
    acc[4]  += a1.x * w; acc[5]  += a1.y * w; acc[6]  += a1.z * w; acc[7]  += a1.w * w;
    acc[8]  += a2.x * w; acc[9]  += a2.y * w; acc[10] += a2.z * w; acc[11] += a2.w * w;
    acc[12] += a3.x * w; acc[13] += a3.y * w; acc[14] += a3.z * w; acc[15] += a3.w * w;
  }
  float bias = (mc == 0) ? proj_b[n] : 0.f;
#pragma unroll
  for (int b = 0; b < BB; ++b)
    atomicAdd(&out[b * DIM + n], acc[b] + bias);
}

extern "C" void kernel_launch(void* const* d_in, const int* in_sizes, int n_in,
                              void* d_out, int out_size, void* d_ws, size_t ws_size,
                              hipStream_t stream) {
  const float* x      = (const float*)d_in[0];
  const float* pos    = (const float*)d_in[1];
  const float* cls    = (const float*)d_in[2];
  const float* qkv_w  = (const float*)d_in[3];
  const float* qkv_b  = (const float*)d_in[4];
  const float* proj_w = (const float*)d_in[5];
  const float* proj_b = (const float*)d_in[6];
  float* ws  = (float*)d_ws;
  float* out = (float*)d_out;

  k0_prep       <<<dim3(16, 64),    256, 0, stream>>>(pos, ws, out);
  k1_q          <<<dim3(8, 64),     256, 0, stream>>>(pos, cls, qkv_w, qkv_b, ws);
  k2_r          <<<dim3(16, 16),    128, 0, stream>>>(qkv_w, pos, cls, ws);
  k3_scores_mfma<<<dim3(8, 16, 4),  256, 0, stream>>>(x, pos, ws);
  k5_pv_mfma    <<<dim3(32, 16),    256, 0, stream>>>(x, cls, ws);
  k6_ao         <<<dim3(8, 64),     256, 0, stream>>>(qkv_w, qkv_b, ws);
  k7_out        <<<dim3(8, 64),     256, 0, stream>>>(proj_w, proj_b, ws, out);
}